// Round 1
// baseline (1072.401 us; speedup 1.0000x reference)
//
#include <hip/hip_runtime.h>
#include <math.h>

#define NN 50000
#define EE 800000
#define OO 4
#define CC 64
#define KDD 16
#define KEYDD 128

__device__ __forceinline__ float wave_sum64(float v) {
  for (int off = 32; off > 0; off >>= 1) v += __shfl_xor(v, off, 64);
  return v;
}
__device__ __forceinline__ float wave_max64(float v) {
  for (int off = 32; off > 0; off >>= 1) v = fmaxf(v, __shfl_xor(v, off, 64));
  return v;
}

// K0: tiny precompute. Gt[c2*64+c1] = sum_k keyW[k,c1]*qryW[k,c2];
// aVec[c] = sum_k keyB[k]*qryW[k,c]; bVec[c] = sum_k qryB[k]*keyW[k,c];
// c0 = keyB.qryB; fk[p,o,c] = dot16(fkb[p,o,:], fkw[c,:])
__global__ void prep_kernel(const float* __restrict__ keyW, const float* __restrict__ keyB,
                            const float* __restrict__ qryW, const float* __restrict__ qryB,
                            const float* __restrict__ fkb, const float* __restrict__ fkw,
                            float* __restrict__ Gt, float* __restrict__ aVec,
                            float* __restrict__ bVec, float* __restrict__ c0,
                            float* __restrict__ fk) {
  int t = threadIdx.x;
  for (int idx = t; idx < CC * CC; idx += 256) {
    int c2 = idx >> 6, c1 = idx & 63;
    float s = 0.f;
    for (int k = 0; k < KEYDD; ++k) s = fmaf(keyW[k * CC + c1], qryW[k * CC + c2], s);
    Gt[idx] = s;
  }
  if (t < CC) {
    float sa = 0.f, sb = 0.f;
    for (int k = 0; k < KEYDD; ++k) {
      sa = fmaf(keyB[k], qryW[k * CC + t], sa);
      sb = fmaf(qryB[k], keyW[k * CC + t], sb);
    }
    aVec[t] = sa; bVec[t] = sb;
  }
  if (t == 0) {
    float s = 0.f;
    for (int k = 0; k < KEYDD; ++k) s = fmaf(keyB[k], qryB[k], s);
    c0[0] = s;
  }
  for (int idx = t; idx < OO * OO * CC; idx += 256) {
    int p = idx >> 8, rem = idx & 255;
    int o = rem >> 6, c = rem & 63;
    float s = 0.f;
    for (int kd = 0; kd < KDD; ++kd)
      s = fmaf(fkb[(p * OO + o) * KDD + kd], fkw[c * KDD + kd], s);
    fk[idx] = s;
  }
}

// K1: u[row,:] = G x[row,:]; sA[row] = aVec.x[row]; sB[row] = bVec.x[row]
// row = n*4+o; block = 4 rows (one node), wave = one row.
__global__ void node_proj_kernel(const float* __restrict__ x, const float* __restrict__ Gt,
                                 const float* __restrict__ aVec, const float* __restrict__ bVec,
                                 float* __restrict__ u, float* __restrict__ sA,
                                 float* __restrict__ sB) {
  __shared__ float gt[CC * CC];
  __shared__ float xs[4 * CC];
  int t = threadIdx.x;
  for (int i = t; i < CC * CC; i += 256) gt[i] = Gt[i];
  int r = t >> 6, c = t & 63;
  int row = blockIdx.x * 4 + r;
  xs[t] = x[row * CC + c];
  __syncthreads();
  const float* xr = &xs[r * CC];
  float acc = 0.f;
  #pragma unroll 8
  for (int c2 = 0; c2 < CC; ++c2) acc = fmaf(gt[c2 * CC + c], xr[c2], acc);
  u[row * CC + c] = acc;
  float xv = xr[c];
  float pa = wave_sum64(aVec[c] * xv);
  float pb = wave_sum64(bVec[c] * xv);
  if (c == 0) { sA[row] = pa; sB[row] = pb; }
}

// K2: logits[e,o] = (x[src,o,:].u[dst,o,:] + sB[src,o] + sA[dst,o] + c0)/sqrt(128)
// one wave per edge (8 edges per wave), block = 4 waves = 32 edges.
__global__ void logits_kernel(const float* __restrict__ x, const float* __restrict__ u,
                              const float* __restrict__ sA, const float* __restrict__ sB,
                              const float* __restrict__ c0p, const int* __restrict__ ei,
                              float* __restrict__ logits, float* __restrict__ partials) {
  int t = threadIdx.x;
  int wave = t >> 6, lane = t & 63;
  const float scale = 0.08838834764831845f;  // 1/sqrt(128)
  float c0 = c0p[0];
  float lmax = -3.4e38f;
  int ebase = blockIdx.x * 32 + wave * 8;
  for (int j = 0; j < 8; ++j) {
    int e = ebase + j;
    int s = ei[e], d = ei[EE + e];
    float l[OO];
    #pragma unroll
    for (int o = 0; o < OO; ++o) {
      float p = x[(s * OO + o) * CC + lane] * u[(d * OO + o) * CC + lane];
      float tot = wave_sum64(p);
      l[o] = (tot + sB[s * OO + o] + sA[d * OO + o] + c0) * scale;
      lmax = fmaxf(lmax, l[o]);
    }
    if (lane == 0)
      *reinterpret_cast<float4*>(&logits[e * 4]) = make_float4(l[0], l[1], l[2], l[3]);
  }
  __shared__ float wmax[4];
  if (lane == 0) wmax[wave] = lmax;
  __syncthreads();
  if (t == 0)
    partials[blockIdx.x] = fmaxf(fmaxf(wmax[0], wmax[1]), fmaxf(wmax[2], wmax[3]));
}

// K3: reduce 25000 partial maxima -> gmax[0]
__global__ void max_reduce_kernel(const float* __restrict__ partials, int n,
                                  float* __restrict__ gmax) {
  __shared__ float wred[16];
  int t = threadIdx.x;
  float m = -3.4e38f;
  for (int i = t; i < n; i += 1024) m = fmaxf(m, partials[i]);
  m = wave_max64(m);
  if ((t & 63) == 0) wred[t >> 6] = m;
  __syncthreads();
  if (t == 0) {
    float mm = -3.4e38f;
    for (int w = 0; w < 16; ++w) mm = fmaxf(mm, wred[w]);
    gmax[0] = mm;
  }
}

// K4: expv = exp(logit - gmax) (in place); denom[dst,o] += expv
__global__ void exp_denom_kernel(float* __restrict__ logits, const int* __restrict__ ei,
                                 const float* __restrict__ gmax, float* __restrict__ denom) {
  int i = blockIdx.x * 256 + threadIdx.x;  // covers E*O exactly
  float g = gmax[0];
  float v = expf(logits[i] - g);
  logits[i] = v;
  int e = i >> 2, o = i & 3;
  int d = ei[EE + e];
  atomicAdd(&denom[d * OO + o], v);
}

// K5a: CSR degree counts
__global__ void count_kernel(const int* __restrict__ ei, int* __restrict__ counts) {
  int e = blockIdx.x * 256 + threadIdx.x;
  if (e < EE) atomicAdd(&counts[ei[EE + e]], 1);
}

// K5b: single-block exclusive scan over counts -> offsets[0..n]
__global__ void scan_kernel(const int* __restrict__ counts, int* __restrict__ offsets, int n) {
  __shared__ int buf[1024];
  __shared__ int carry;
  int t = threadIdx.x;
  if (t == 0) carry = 0;
  __syncthreads();
  for (int base = 0; base < n; base += 1024) {
    int i = base + t;
    int v = (i < n) ? counts[i] : 0;
    buf[t] = v;
    __syncthreads();
    for (int off = 1; off < 1024; off <<= 1) {
      int a = buf[t];
      int b = (t >= off) ? buf[t - off] : 0;
      __syncthreads();
      buf[t] = a + b;
      __syncthreads();
    }
    int incl = buf[t];
    if (i < n) offsets[i] = carry + (incl - v);
    __syncthreads();
    if (t == 1023) carry += buf[1023];
    __syncthreads();
  }
  if (t == 0) offsets[n] = carry;
}

// K5c: fill CSR edge list
__global__ void fill_kernel(const int* __restrict__ ei, const int* __restrict__ offsets,
                            int* __restrict__ cursor, int* __restrict__ edge_list) {
  int e = blockIdx.x * 256 + threadIdx.x;
  if (e < EE) {
    int d = ei[EE + e];
    int pos = offsets[d] + atomicAdd(&cursor[d], 1);
    edge_list[pos] = e;
  }
}

// K6: per-node gather-aggregate + fiber mixing + bias. block = node, thread = (o,c).
__global__ void aggregate_kernel(const float* __restrict__ x, const float* __restrict__ kb,
                                 const float* __restrict__ kW, const float* __restrict__ expv,
                                 const float* __restrict__ denom, const int* __restrict__ ei,
                                 const int* __restrict__ offsets,
                                 const int* __restrict__ edge_list,
                                 const float* __restrict__ fkg, const float* __restrict__ bias,
                                 float* __restrict__ out) {
  __shared__ float fk[OO * OO * CC];
  __shared__ float kbl[OO * KDD];
  __shared__ float x1[OO * CC];
  __shared__ int src_sh;
  int n = blockIdx.x;
  int t = threadIdx.x;
  int o = t >> 6, c = t & 63;
  for (int i = t; i < OO * OO * CC; i += 256) fk[i] = fkg[i];
  float kw[KDD];
  #pragma unroll
  for (int kd = 0; kd < KDD; ++kd) kw[kd] = kW[c * KDD + kd];
  float invd = 1.0f / (denom[n * OO + o] + 1e-6f);
  int start = offsets[n], end = offsets[n + 1];
  float acc = 0.f;
  for (int j = start; j < end; ++j) {
    int e = edge_list[j];
    __syncthreads();  // protect kbl/src_sh from previous iteration readers
    if (t < OO * KDD) kbl[t] = kb[e * (OO * KDD) + t];
    if (t == 64) src_sh = ei[e];
    __syncthreads();
    int s = src_sh;
    float att = expv[e * OO + o] * invd;
    float k = 0.f;
    #pragma unroll
    for (int kd = 0; kd < KDD; ++kd) k = fmaf(kbl[o * KDD + kd], kw[kd], k);
    float xv = x[(s * OO + o) * CC + c];
    acc = fmaf(xv, k * att, acc);
  }
  __syncthreads();
  x1[t] = acc;  // x1[o*64 + c]
  __syncthreads();
  int p = o;  // reuse thread mapping for output orientation
  float s2 = 0.f;
  #pragma unroll
  for (int oo = 0; oo < OO; ++oo)
    s2 = fmaf(x1[oo * CC + c], fk[p * (OO * CC) + oo * CC + c], s2);
  out[n * (OO * CC) + t] = 0.25f * s2 + bias[c];
}

extern "C" void kernel_launch(void* const* d_in, const int* in_sizes, int n_in,
                              void* d_out, int out_size, void* d_ws, size_t ws_size,
                              hipStream_t stream) {
  const float* x    = (const float*)d_in[0];
  const float* kb   = (const float*)d_in[1];
  const float* fkb  = (const float*)d_in[2];
  const int*   ei   = (const int*)d_in[3];
  const float* kW   = (const float*)d_in[4];
  const float* fkW  = (const float*)d_in[5];
  const float* keyW = (const float*)d_in[6];
  const float* keyB = (const float*)d_in[7];
  const float* qryW = (const float*)d_in[8];
  const float* qryB = (const float*)d_in[9];
  const float* bias = (const float*)d_in[10];
  float* out = (float*)d_out;

  // workspace layout (floats then ints), ~70.3 MB total
  float* wsf   = (float*)d_ws;
  float* Gt    = wsf;                       // 4096
  float* aVec  = Gt + 4096;                 // 64
  float* bVec  = aVec + 64;                 // 64
  float* c0    = bVec + 64;                 // 1 (+pad)
  float* gmax  = c0 + 1;                    // 1
  float* fk    = c0 + 64;                   // 1024
  float* u     = fk + 1024;                 // 12.8M  (16B-aligned offset)
  float* sA    = u + (size_t)NN * OO * CC;  // 200000
  float* sB    = sA + NN * OO;              // 200000
  float* logits = sB + NN * OO;             // 3.2M (doubles as expv)
  float* denom = logits + (size_t)EE * OO;  // 200000
  float* partials = denom + NN * OO;        // 25000
  int* counts    = (int*)(partials + 25000);
  int* cursor    = counts + NN;
  int* offsets   = cursor + NN;
  int* edge_list = offsets + NN + 1;

  hipMemsetAsync(denom, 0, (size_t)NN * OO * sizeof(float), stream);
  hipMemsetAsync(counts, 0, (size_t)NN * sizeof(int), stream);
  hipMemsetAsync(cursor, 0, (size_t)NN * sizeof(int), stream);

  prep_kernel<<<1, 256, 0, stream>>>(keyW, keyB, qryW, qryB, fkb, fkW, Gt, aVec, bVec, c0, fk);
  node_proj_kernel<<<NN, 256, 0, stream>>>(x, Gt, aVec, bVec, u, sA, sB);
  logits_kernel<<<EE / 32, 256, 0, stream>>>(x, u, sA, sB, c0, ei, logits, partials);
  max_reduce_kernel<<<1, 1024, 0, stream>>>(partials, EE / 32, gmax);
  exp_denom_kernel<<<EE * OO / 256, 256, 0, stream>>>(logits, ei, gmax, denom);
  count_kernel<<<(EE + 255) / 256, 256, 0, stream>>>(ei, counts);
  scan_kernel<<<1, 1024, 0, stream>>>(counts, offsets, NN);
  fill_kernel<<<(EE + 255) / 256, 256, 0, stream>>>(ei, offsets, cursor, edge_list);
  aggregate_kernel<<<NN, 256, 0, stream>>>(x, kb, kW, logits, denom, ei, offsets, edge_list,
                                           fk, bias, out);
}